// Round 2
// baseline (135.499 us; speedup 1.0000x reference)
//
#include <hip/hip_runtime.h>
#include <hip/hip_fp16.h>

// Problem constants
#define N_ 64
#define H_ 128
#define E_ 32
#define H1_ 128
#define H2_ 64
#define S_ 4096
// Wlin offsets: [users 0:32][items 32:64][langs 64:80][onehot 80:4176][tcf 4176:12368]
#define OFF_ITEMS 32
#define OFF_LANGS 64
#define OFF_ONEHOT 80
#define OFF_TCF 4176
#define OFF_TCF2 8272

typedef _Float16 half8 __attribute__((ext_vector_type(8)));
typedef short short8 __attribute__((ext_vector_type(8)));
typedef float floatx4 __attribute__((ext_vector_type(4)));

// ---------------------------------------------------------------------------
// Kernel 0: shuffle W2 (128x64 f32) into per-lane MFMA B-fragment order (f16).
// Fragment order: idx = ((((kk*4)+nt)*4+hi)*16+lo)*8 + e
// value = W2[(32*kk + 8*hi + e)*64 + (16*nt + lo)]
// grid 32 x 256
__global__ void build_w2frag(const float* __restrict__ W2, _Float16* __restrict__ W2f) {
    int f = blockIdx.x * 256 + threadIdx.x;   // 0..8191
    int e  = f & 7;
    int lo = (f >> 3) & 15;
    int hi = (f >> 7) & 3;
    int nt = (f >> 9) & 3;
    int kk = f >> 11;
    W2f[f] = (_Float16)W2[(32 * kk + 8 * hi + e) * 64 + (16 * nt + lo)];
}

// ---------------------------------------------------------------------------
// Kernel 1: a[nh][k] = b1[k] + sum_e emb[e]*W1[e][k] ;  b[nh][k] = sum_e emb[e]*W1[32+e][k]
// stored as f16. grid 512 x 256 (16 rows per block), W1 staged in LDS.
__global__ void build_ab(const int* __restrict__ skills,
                         const float* __restrict__ emb_table,
                         const float* __restrict__ W1,
                         const float* __restrict__ b1,
                         _Float16* __restrict__ aT, _Float16* __restrict__ bT) {
    __shared__ float W1s[64 * 128];     // 32 KB
    __shared__ float embs[16][32];

    int tid = threadIdx.x;
    for (int idx = tid; idx < 64 * 128; idx += 256) W1s[idx] = W1[idx];

    int r0 = blockIdx.x * 16;
    for (int idx = tid; idx < 16 * 32; idx += 256) {
        int r = idx >> 5, e = idx & 31;
        int sk = skills[r0 + r];
        embs[r][e] = emb_table[sk * 32 + e];
    }
    __syncthreads();

    int k = tid & 127;
    int rh = tid >> 7;   // 0..1
    float b1k = b1[k];
    for (int rr = 0; rr < 16; rr += 2) {
        int r = rr + rh;
        float a = b1k, b = 0.f;
        #pragma unroll
        for (int e = 0; e < 32; e++) {
            float ev = embs[r][e];
            a += ev * W1s[e * 128 + k];
            b += ev * W1s[(e + 32) * 128 + k];
        }
        size_t row = (size_t)(r0 + r) * 128;
        aT[row + k] = (_Float16)a;
        bT[row + k] = (_Float16)b;
    }
}

// ---------------------------------------------------------------------------
// Kernel 2: pairwise MLP over the lower triangle.
// Block = 32x32 (i,j) tile of one sample n. 256 threads = 4 waves.
// Each wave processes 16-row groups; all 16 rows of a group share the same i.
// h1 = relu(a_i + b_j) in f16 -> MFMA 16x16x32_f16 vs W2 -> relu,dot(Ws),tanh
// -> accumulate per-i sums into segT/segC via atomics.
__global__ __launch_bounds__(256) void pair_mlp(
    const _Float16* __restrict__ aT, const _Float16* __restrict__ bT,
    const _Float16* __restrict__ W2f, const float* __restrict__ targets,
    const float* __restrict__ b2, const float* __restrict__ Ws,
    const float* __restrict__ bs,
    float* __restrict__ segT, float* __restrict__ segC) {

    int bid = blockIdx.x;
    int n = bid / 10;
    int t = bid % 10;
    int ti = 0;
    while ((ti + 1) * (ti + 2) / 2 <= t) ti++;
    int tj = t - ti * (ti + 1) / 2;
    int i0 = ti * 32, j0 = tj * 32;
    bool diag = (ti == tj);

    __shared__ __align__(16) _Float16 aL[32][136];  // +8 pad: spreads rows across banks
    __shared__ __align__(16) _Float16 bL[32][136];
    __shared__ float tgt[32];

    int tid = threadIdx.x;
    // stage a rows [i0,i0+32), b rows [j0,j0+32): 32 rows x 16 chunks of 16B
    for (int idx = tid; idx < 512; idx += 256) {
        int r = idx >> 4, c = idx & 15;
        *(uint4*)(&aL[r][c * 8]) = *(const uint4*)(aT + (size_t)(n * H_ + i0 + r) * 128 + c * 8);
        *(uint4*)(&bL[r][c * 8]) = *(const uint4*)(bT + (size_t)(n * H_ + j0 + r) * 128 + c * 8);
    }
    if (tid < 32) tgt[tid] = targets[n * H_ + j0 + tid];

    int lane = tid & 63, wv = tid >> 6;
    int hi = lane >> 4, lo = lane & 15;

    // B fragments: entire W2 distributed across the wave (64 VGPRs/lane)
    half8 wfrag[4][4];
    #pragma unroll
    for (int kk = 0; kk < 4; kk++)
        #pragma unroll
        for (int nt = 0; nt < 4; nt++)
            wfrag[kk][nt] = *(const half8*)(W2f + ((((kk * 4 + nt) * 4 + hi) * 16 + lo) * 8));

    float b2v[4], wsv[4];
    #pragma unroll
    for (int nt = 0; nt < 4; nt++) {
        b2v[nt] = b2[16 * nt + lo];
        wsv[nt] = Ws[16 * nt + lo];
    }
    float bsv = bs[0];

    __syncthreads();

    for (int g = wv; g < 64; g += 4) {
        int li = g >> 1;        // i - i0 (same for all 16 rows of the group)
        int hf = g & 1;         // which 16-j half
        if (diag && li <= 16 * hf) continue;   // no valid pairs in group

        const _Float16* arow = &aL[li][0];
        const _Float16* brow = &bL[16 * hf + lo][0];   // lane's A-row = lo -> its j row

        floatx4 acc[4];
        #pragma unroll
        for (int nt = 0; nt < 4; nt++) acc[nt] = (floatx4){0.f, 0.f, 0.f, 0.f};

        #pragma unroll
        for (int kk = 0; kk < 4; kk++) {
            half8 av = *(const half8*)(arow + 32 * kk + 8 * hi);  // broadcast across lo
            half8 bv = *(const half8*)(brow + 32 * kk + 8 * hi);
            half8 s = av + bv;                       // v_pk_add_f16
            // relu via sign-bit trick
            short8 bits = __builtin_bit_cast(short8, s);
            short8 sgn = bits >> 15;
            bits &= ~sgn;
            half8 h = __builtin_bit_cast(half8, bits);
            acc[0] = __builtin_amdgcn_mfma_f32_16x16x32_f16(h, wfrag[kk][0], acc[0], 0, 0, 0);
            acc[1] = __builtin_amdgcn_mfma_f32_16x16x32_f16(h, wfrag[kk][1], acc[1], 0, 0, 0);
            acc[2] = __builtin_amdgcn_mfma_f32_16x16x32_f16(h, wfrag[kk][2], acc[2], 0, 0, 0);
            acc[3] = __builtin_amdgcn_mfma_f32_16x16x32_f16(h, wfrag[kk][3], acc[3], 0, 0, 0);
        }

        // epilogue: h2 = relu(acc + b2); partial = sum_cols h2*Ws
        // lane holds cols 16*nt+lo for rows 4*hi+r4
        float part[4];
        #pragma unroll
        for (int r4 = 0; r4 < 4; r4++) {
            float p = 0.f;
            #pragma unroll
            for (int nt = 0; nt < 4; nt++)
                p += fmaxf(acc[nt][r4] + b2v[nt], 0.f) * wsv[nt];
            part[r4] = p;
        }
        // reduce across the 16 lanes of a hi-group (cols)
        #pragma unroll
        for (int m = 1; m <= 8; m <<= 1) {
            #pragma unroll
            for (int r4 = 0; r4 < 4; r4++)
                part[r4] += __shfl_xor(part[r4], m, 64);
        }
        // sim + per-i sums
        float sumT = 0.f, sumC = 0.f;
        #pragma unroll
        for (int r4 = 0; r4 < 4; r4++) {
            int srow = 4 * hi + r4;            // row within group
            int lj = 16 * hf + srow;           // j - j0
            bool valid = (!diag) || (li > lj);
            float x = part[r4] + bsv;
            float e2 = __expf(2.f * x);
            float sv = (e2 - 1.f) / (e2 + 1.f);  // tanh
            sv = valid ? sv : 0.f;
            sumT += sv;
            sumC += sv * tgt[lj];
        }
        // reduce across hi groups (lanes within a hi-group hold identical values,
        // xor16/32 only mixes hi bits)
        sumT += __shfl_xor(sumT, 16, 64);
        sumT += __shfl_xor(sumT, 32, 64);
        sumC += __shfl_xor(sumC, 16, 64);
        sumC += __shfl_xor(sumC, 32, 64);
        if (lane == 0) {
            atomicAdd(&segT[n * H_ + i0 + li], sumT);
            atomicAdd(&segC[n * H_ + i0 + li], sumC);
        }
    }
}

// ---------------------------------------------------------------------------
// Kernel 3: per-(n,h) final linear + sigmoid + masked BCE partial sums.
// grid 64 x 128 (one block per n)
__global__ void finalize(const int* __restrict__ skills,
                         const float* __restrict__ targets,
                         const float* __restrict__ users,
                         const float* __restrict__ items,
                         const float* __restrict__ langs,
                         const void* __restrict__ mask,
                         const float* __restrict__ Wlin,
                         const float* __restrict__ blin,
                         const float* __restrict__ segT,
                         const float* __restrict__ segC,
                         float* __restrict__ out,
                         float* __restrict__ accums) {
    int n = blockIdx.x, h = threadIdx.x;
    int nh = n * H_ + h;
    int sk = skills[nh];

    // --- mask dtype sniff: bool (1B) vs int32 (4B). Reading 64 words = 256 B
    // is in-bounds under either layout (bool buffer is 8192 B). If any word
    // exceeds 1, the buffer must be packed bytes (P[miss] ~ 0.008^64).
    const unsigned* mw = (const unsigned*)mask;
    bool byte_layout = false;
    #pragma unroll 8
    for (int q = 0; q < 64; q++) byte_layout |= (mw[q] > 1u);
    float m = byte_layout ? (((const unsigned char*)mask)[nh] ? 1.f : 0.f)
                          : (mw[nh] ? 1.f : 0.f);

    // per-n constant part: users.Wlin[0:32] + tcf.Wlin[tcf] (+blin)
    float tterm = segT[nh] * Wlin[OFF_TCF + sk] + segC[nh] * Wlin[OFF_TCF2 + sk];
    if (h < 32) tterm += users[n * 32 + h] * Wlin[h];

    __shared__ float red[128];
    red[h] = tterm;
    __syncthreads();
    for (int s = 64; s > 0; s >>= 1) {
        if (h < s) red[h] += red[h + s];
        __syncthreads();
    }
    float c = red[0] + blin[0];
    __syncthreads();

    float z = c + Wlin[OFF_ONEHOT + sk];
    #pragma unroll
    for (int i = 0; i < 32; i++) z += items[(size_t)nh * 32 + i] * Wlin[OFF_ITEMS + i];
    #pragma unroll
    for (int l = 0; l < 16; l++) z += langs[(size_t)nh * 16 + l] * Wlin[OFF_LANGS + l];

    out[1 + nh] = 1.f / (1.f + __expf(-z));

    float y = targets[nh];
    float bce = fmaxf(z, 0.f) - z * y + log1pf(__expf(-fabsf(z)));

    red[h] = bce * m;
    __syncthreads();
    for (int s = 64; s > 0; s >>= 1) {
        if (h < s) red[h] += red[h + s];
        __syncthreads();
    }
    if (h == 0) atomicAdd(&accums[0], red[0]);
    __syncthreads();

    red[h] = m;
    __syncthreads();
    for (int s = 64; s > 0; s >>= 1) {
        if (h < s) red[h] += red[h + s];
        __syncthreads();
    }
    if (h == 0) atomicAdd(&accums[1], red[0]);
}

__global__ void finalize_loss(const float* __restrict__ accums, float* __restrict__ out) {
    out[0] = accums[0] / fmaxf(accums[1], 1.f);
}

// ---------------------------------------------------------------------------
extern "C" void kernel_launch(void* const* d_in, const int* in_sizes, int n_in,
                              void* d_out, int out_size, void* d_ws, size_t ws_size,
                              hipStream_t stream) {
    const int*   skills  = (const int*)d_in[0];
    const float* targets = (const float*)d_in[1];
    const float* users   = (const float*)d_in[2];
    const float* items   = (const float*)d_in[3];
    const float* langs   = (const float*)d_in[4];
    const void*  mask    = (const void*)d_in[5];
    const float* emb     = (const float*)d_in[6];
    const float* W1      = (const float*)d_in[7];
    const float* b1      = (const float*)d_in[8];
    const float* W2      = (const float*)d_in[9];
    const float* b2      = (const float*)d_in[10];
    const float* Ws      = (const float*)d_in[11];
    const float* bs      = (const float*)d_in[12];
    const float* Wlin    = (const float*)d_in[13];
    const float* blin    = (const float*)d_in[14];

    char* ws = (char*)d_ws;
    _Float16* aT  = (_Float16*)(ws);                       // 8192*128 f16 = 2 MB
    _Float16* bT  = (_Float16*)(ws + (2u << 20));          // 2 MB
    _Float16* W2f = (_Float16*)(ws + (4u << 20));          // 16 KB
    float* segT   = (float*)(ws + (4u << 20) + 16384);     // 32 KB
    float* segC   = segT + N_ * H_;                        // 32 KB
    float* accums = segC + N_ * H_;                        // 8 B

    // zero the accumulation region (ws is poisoned before every call)
    hipMemsetAsync(segT, 0, (size_t)(2 * N_ * H_ + 2) * sizeof(float), stream);

    build_w2frag<<<32, 256, 0, stream>>>(W2, W2f);
    build_ab<<<512, 256, 0, stream>>>(skills, emb, W1, b1, aT, bT);
    pair_mlp<<<N_ * 10, 256, 0, stream>>>(aT, bT, W2f, targets, b2, Ws, bs, segT, segC);
    finalize<<<N_, H_, 0, stream>>>(skills, targets, users, items, langs, mask,
                                    Wlin, blin, segT, segC, (float*)d_out, accums);
    finalize_loss<<<1, 1, 0, stream>>>(accums, (float*)d_out);
}

// Round 3
// 134.385 us; speedup vs baseline: 1.0083x; 1.0083x over previous
//
#include <hip/hip_runtime.h>
#include <hip/hip_fp16.h>

// Problem constants
#define N_ 64
#define H_ 128
#define E_ 32
#define H1_ 128
#define H2_ 64
#define S_ 4096
// Wlin offsets: [users 0:32][items 32:64][langs 64:80][onehot 80:4176][tcf 4176:12368]
#define OFF_ITEMS 32
#define OFF_LANGS 64
#define OFF_ONEHOT 80
#define OFF_TCF 4176
#define OFF_TCF2 8272

typedef _Float16 half8 __attribute__((ext_vector_type(8)));
typedef short short8 __attribute__((ext_vector_type(8)));
typedef float floatx4 __attribute__((ext_vector_type(4)));

// ---------------------------------------------------------------------------
// Kernel 1 (prep): blocks 0..511 build a/b; block 512 builds W2f fragments and
// zeroes segT/segC/accums/counter (replaces hipMemsetAsync + build_w2frag).
//   a[nh][k] = b1[k] + sum_e emb[e]*W1[e][k] ; b[nh][k] = sum_e emb[e]*W1[32+e][k]
__global__ __launch_bounds__(256) void prep(
    const int* __restrict__ skills, const float* __restrict__ emb_table,
    const float* __restrict__ W1, const float* __restrict__ b1,
    const float* __restrict__ W2,
    _Float16* __restrict__ aT, _Float16* __restrict__ bT,
    _Float16* __restrict__ W2f, float* __restrict__ zero_region) {

    int tid = threadIdx.x;

    if (blockIdx.x == 512) {
        // zero segT(8192) + segC(8192) + accums(2) + counter(1) + pad
        for (int idx = tid; idx < 2 * N_ * H_ + 4; idx += 256)
            zero_region[idx] = 0.f;
        // W2 (128x64 f32) -> per-lane MFMA B-fragment order (f16)
        // idx = ((((kk*4)+nt)*4+hi)*16+lo)*8 + e ; val = W2[(32kk+8hi+e)*64 + 16nt+lo]
        for (int f = tid; f < 8192; f += 256) {
            int e  = f & 7;
            int lo = (f >> 3) & 15;
            int hi = (f >> 7) & 3;
            int nt = (f >> 9) & 3;
            int kk = f >> 11;
            W2f[f] = (_Float16)W2[(32 * kk + 8 * hi + e) * 64 + (16 * nt + lo)];
        }
        return;
    }

    __shared__ float W1s[64 * 128];     // 32 KB
    __shared__ float embs[16][32];

    for (int idx = tid; idx < 64 * 128; idx += 256) W1s[idx] = W1[idx];

    int r0 = blockIdx.x * 16;
    for (int idx = tid; idx < 16 * 32; idx += 256) {
        int r = idx >> 5, e = idx & 31;
        int sk = skills[r0 + r];
        embs[r][e] = emb_table[sk * 32 + e];
    }
    __syncthreads();

    int k = tid & 127;
    int rh = tid >> 7;   // 0..1
    float b1k = b1[k];
    for (int rr = 0; rr < 16; rr += 2) {
        int r = rr + rh;
        float a = b1k, b = 0.f;
        #pragma unroll
        for (int e = 0; e < 32; e++) {
            float ev = embs[r][e];
            a += ev * W1s[e * 128 + k];
            b += ev * W1s[(e + 32) * 128 + k];
        }
        size_t row = (size_t)(r0 + r) * 128;
        aT[row + k] = (_Float16)a;
        bT[row + k] = (_Float16)b;
    }
}

// ---------------------------------------------------------------------------
// Kernel 2: pairwise MLP over the lower triangle.
// Block = 32x32 (i,j) tile of one sample n. 256 threads = 4 waves.
// Each wave processes 16-row groups; all 16 rows of a group share the same i.
// h1 = relu(a_i + b_j) f16 -> MFMA 16x16x32_f16 vs W2 -> relu,dot(Ws),tanh
// -> per-block LDS seg accumulation (ds_add_f32) -> one global atomic per i.
__global__ __launch_bounds__(256) void pair_mlp(
    const _Float16* __restrict__ aT, const _Float16* __restrict__ bT,
    const _Float16* __restrict__ W2f, const float* __restrict__ targets,
    const float* __restrict__ b2, const float* __restrict__ Ws,
    const float* __restrict__ bs,
    float* __restrict__ segT, float* __restrict__ segC) {

    int bid = blockIdx.x;
    int n = bid / 10;
    int t = bid % 10;
    int ti = 0;
    while ((ti + 1) * (ti + 2) / 2 <= t) ti++;
    int tj = t - ti * (ti + 1) / 2;
    int i0 = ti * 32, j0 = tj * 32;
    bool diag = (ti == tj);

    __shared__ __align__(16) _Float16 aL[32][136];  // +8 pad: 2-way banks (free)
    __shared__ __align__(16) _Float16 bL[32][136];
    __shared__ float tgt[32];
    __shared__ float sT[32], sC[32];

    int tid = threadIdx.x;
    // stage a rows [i0,i0+32), b rows [j0,j0+32): 32 rows x 16 chunks of 16B
    for (int idx = tid; idx < 512; idx += 256) {
        int r = idx >> 4, c = idx & 15;
        *(uint4*)(&aL[r][c * 8]) = *(const uint4*)(aT + (size_t)(n * H_ + i0 + r) * 128 + c * 8);
        *(uint4*)(&bL[r][c * 8]) = *(const uint4*)(bT + (size_t)(n * H_ + j0 + r) * 128 + c * 8);
    }
    if (tid < 32) {
        tgt[tid] = targets[n * H_ + j0 + tid];
        sT[tid] = 0.f;
        sC[tid] = 0.f;
    }

    int lane = tid & 63, wv = tid >> 6;
    int hi = lane >> 4, lo = lane & 15;

    // B fragments: entire W2 distributed across the wave (64 VGPRs/lane)
    half8 wfrag[4][4];
    #pragma unroll
    for (int kk = 0; kk < 4; kk++)
        #pragma unroll
        for (int nt = 0; nt < 4; nt++)
            wfrag[kk][nt] = *(const half8*)(W2f + ((((kk * 4 + nt) * 4 + hi) * 16 + lo) * 8));

    float b2v[4], wsv[4];
    #pragma unroll
    for (int nt = 0; nt < 4; nt++) {
        b2v[nt] = b2[16 * nt + lo];
        wsv[nt] = Ws[16 * nt + lo];
    }
    float bsv = bs[0];

    __syncthreads();

    for (int g = wv; g < 64; g += 4) {
        int li = g >> 1;        // i - i0 (same for all 16 rows of the group)
        int hf = g & 1;         // which 16-j half
        if (diag && li <= 16 * hf) continue;   // no valid pairs in group

        const _Float16* arow = &aL[li][0];
        const _Float16* brow = &bL[16 * hf + lo][0];   // lane's A-row = its j row

        floatx4 acc[4];
        #pragma unroll
        for (int nt = 0; nt < 4; nt++) acc[nt] = (floatx4){0.f, 0.f, 0.f, 0.f};

        #pragma unroll
        for (int kk = 0; kk < 4; kk++) {
            half8 av = *(const half8*)(arow + 32 * kk + 8 * hi);  // broadcast
            half8 bv = *(const half8*)(brow + 32 * kk + 8 * hi);
            half8 s = av + bv;                       // v_pk_add_f16
            // relu via sign-bit trick
            short8 bits = __builtin_bit_cast(short8, s);
            short8 sgn = bits >> 15;
            bits &= ~sgn;
            half8 h = __builtin_bit_cast(half8, bits);
            acc[0] = __builtin_amdgcn_mfma_f32_16x16x32_f16(h, wfrag[kk][0], acc[0], 0, 0, 0);
            acc[1] = __builtin_amdgcn_mfma_f32_16x16x32_f16(h, wfrag[kk][1], acc[1], 0, 0, 0);
            acc[2] = __builtin_amdgcn_mfma_f32_16x16x32_f16(h, wfrag[kk][2], acc[2], 0, 0, 0);
            acc[3] = __builtin_amdgcn_mfma_f32_16x16x32_f16(h, wfrag[kk][3], acc[3], 0, 0, 0);
        }

        // epilogue: h2 = relu(acc + b2); partial = sum_cols h2*Ws
        // lane holds cols 16*nt+lo for rows 4*hi+r4
        float part[4];
        #pragma unroll
        for (int r4 = 0; r4 < 4; r4++) {
            float p = 0.f;
            #pragma unroll
            for (int nt = 0; nt < 4; nt++)
                p += fmaxf(acc[nt][r4] + b2v[nt], 0.f) * wsv[nt];
            part[r4] = p;
        }
        // reduce across the 16 lanes of a hi-group (cols)
        #pragma unroll
        for (int m = 1; m <= 8; m <<= 1) {
            #pragma unroll
            for (int r4 = 0; r4 < 4; r4++)
                part[r4] += __shfl_xor(part[r4], m, 64);
        }
        // sim + per-i partial for this hi-group's 4 rows
        float sumT = 0.f, sumC = 0.f;
        #pragma unroll
        for (int r4 = 0; r4 < 4; r4++) {
            int srow = 4 * hi + r4;            // row within group
            int lj = 16 * hf + srow;           // j - j0
            bool valid = (!diag) || (li > lj);
            float x = part[r4] + bsv;
            float e2 = __expf(2.f * x);
            float sv = (e2 - 1.f) / (e2 + 1.f);  // tanh
            sv = valid ? sv : 0.f;
            sumT += sv;
            sumC += sv * tgt[lj];
        }
        if (lo == 0) {                          // one lane per hi-group
            atomicAdd(&sT[li], sumT);           // ds_add_f32
            atomicAdd(&sC[li], sumC);
        }
    }

    __syncthreads();
    if (tid < 32) {
        atomicAdd(&segT[n * H_ + i0 + tid], sT[tid]);
        atomicAdd(&segC[n * H_ + i0 + tid], sC[tid]);
    }
}

// ---------------------------------------------------------------------------
// Kernel 3: per-(n,h) final linear + sigmoid + masked BCE; last block divides.
// grid 64 x 128 (one block per n)
__global__ void finalize(const int* __restrict__ skills,
                         const float* __restrict__ targets,
                         const float* __restrict__ users,
                         const float* __restrict__ items,
                         const float* __restrict__ langs,
                         const void* __restrict__ mask,
                         const float* __restrict__ Wlin,
                         const float* __restrict__ blin,
                         const float* __restrict__ segT,
                         const float* __restrict__ segC,
                         float* __restrict__ out,
                         float* __restrict__ accums,
                         int* __restrict__ counter) {
    int n = blockIdx.x, h = threadIdx.x;
    int nh = n * H_ + h;
    int sk = skills[nh];

    // mask dtype sniff: bool(1B) vs int32(4B). 16 words, in-bounds either way.
    // P[all 16 words <=1 under byte layout] = 0.2^48 ~ 3e-34.
    const unsigned* mw = (const unsigned*)mask;
    bool byte_layout = false;
    #pragma unroll
    for (int q = 0; q < 16; q++) byte_layout |= (mw[q] > 1u);
    float m = byte_layout ? (((const unsigned char*)mask)[nh] ? 1.f : 0.f)
                          : (mw[nh] ? 1.f : 0.f);

    // per-n constant part: users.Wlin[0:32] + tcf-dot (+blin)
    float tterm = segT[nh] * Wlin[OFF_TCF + sk] + segC[nh] * Wlin[OFF_TCF2 + sk];
    if (h < 32) tterm += users[n * 32 + h] * Wlin[h];

    __shared__ float red[128];
    red[h] = tterm;
    __syncthreads();
    for (int s = 64; s > 0; s >>= 1) {
        if (h < s) red[h] += red[h + s];
        __syncthreads();
    }
    float c = red[0] + blin[0];

    float z = c + Wlin[OFF_ONEHOT + sk];
    const float4* ip = (const float4*)(items + (size_t)nh * 32);
    #pragma unroll
    for (int i4 = 0; i4 < 8; i4++) {
        float4 v = ip[i4];
        z += v.x * Wlin[OFF_ITEMS + 4 * i4]     + v.y * Wlin[OFF_ITEMS + 4 * i4 + 1]
           + v.z * Wlin[OFF_ITEMS + 4 * i4 + 2] + v.w * Wlin[OFF_ITEMS + 4 * i4 + 3];
    }
    const float4* lp = (const float4*)(langs + (size_t)nh * 16);
    #pragma unroll
    for (int l4 = 0; l4 < 4; l4++) {
        float4 v = lp[l4];
        z += v.x * Wlin[OFF_LANGS + 4 * l4]     + v.y * Wlin[OFF_LANGS + 4 * l4 + 1]
           + v.z * Wlin[OFF_LANGS + 4 * l4 + 2] + v.w * Wlin[OFF_LANGS + 4 * l4 + 3];
    }

    out[1 + nh] = 1.f / (1.f + __expf(-z));

    float y = targets[nh];
    float bce = fmaxf(z, 0.f) - z * y + log1pf(__expf(-fabsf(z)));

    __shared__ float2 red2[128];
    red2[h] = make_float2(bce * m, m);
    __syncthreads();
    for (int s = 64; s > 0; s >>= 1) {
        if (h < s) {
            red2[h].x += red2[h + s].x;
            red2[h].y += red2[h + s].y;
        }
        __syncthreads();
    }
    if (h == 0) {
        atomicAdd(&accums[0], red2[0].x);
        atomicAdd(&accums[1], red2[0].y);
        __threadfence();
        if (atomicAdd(counter, 1) == N_ - 1) {       // last block overall
            float a = atomicAdd(&accums[0], 0.f);    // device-coherent read
            float b = atomicAdd(&accums[1], 0.f);
            out[0] = a / fmaxf(b, 1.f);
        }
    }
}

// ---------------------------------------------------------------------------
extern "C" void kernel_launch(void* const* d_in, const int* in_sizes, int n_in,
                              void* d_out, int out_size, void* d_ws, size_t ws_size,
                              hipStream_t stream) {
    const int*   skills  = (const int*)d_in[0];
    const float* targets = (const float*)d_in[1];
    const float* users   = (const float*)d_in[2];
    const float* items   = (const float*)d_in[3];
    const float* langs   = (const float*)d_in[4];
    const void*  mask    = (const void*)d_in[5];
    const float* emb     = (const float*)d_in[6];
    const float* W1      = (const float*)d_in[7];
    const float* b1      = (const float*)d_in[8];
    const float* W2      = (const float*)d_in[9];
    const float* b2      = (const float*)d_in[10];
    const float* Ws      = (const float*)d_in[11];
    const float* bs      = (const float*)d_in[12];
    const float* Wlin    = (const float*)d_in[13];
    const float* blin    = (const float*)d_in[14];

    char* ws = (char*)d_ws;
    _Float16* aT  = (_Float16*)(ws);                       // 8192*128 f16 = 2 MB
    _Float16* bT  = (_Float16*)(ws + (2u << 20));          // 2 MB
    _Float16* W2f = (_Float16*)(ws + (4u << 20));          // 16 KB
    float* segT   = (float*)(ws + (4u << 20) + 16384);     // 32 KB
    float* segC   = segT + N_ * H_;                        // 32 KB
    float* accums = segC + N_ * H_;                        // 8 B
    int*   counter = (int*)(accums + 2);                   // 4 B

    prep<<<513, 256, 0, stream>>>(skills, emb, W1, b1, W2, aT, bT, W2f, segT);
    pair_mlp<<<N_ * 10, 256, 0, stream>>>(aT, bT, W2f, targets, b2, Ws, bs, segT, segC);
    finalize<<<N_, H_, 0, stream>>>(skills, targets, users, items, langs, mask,
                                    Wlin, blin, segT, segC, (float*)d_out, accums, counter);
}

// Round 4
// 121.265 us; speedup vs baseline: 1.1174x; 1.1082x over previous
//
#include <hip/hip_runtime.h>
#include <hip/hip_fp16.h>

// Problem constants
#define N_ 64
#define H_ 128
#define E_ 32
#define H1_ 128
#define H2_ 64
#define S_ 4096
// Wlin offsets: [users 0:32][items 32:64][langs 64:80][onehot 80:4176][tcf 4176:12368]
#define OFF_ITEMS 32
#define OFF_LANGS 64
#define OFF_ONEHOT 80
#define OFF_TCF 4176
#define OFF_TCF2 8272

typedef _Float16 half8 __attribute__((ext_vector_type(8)));
typedef short short8 __attribute__((ext_vector_type(8)));
typedef float floatx4 __attribute__((ext_vector_type(4)));

// ---------------------------------------------------------------------------
// Kernel 1: fused build + pairwise MLP over the lower triangle.
// Block = 32x32 (i,j) tile of one sample n. 256 threads = 4 waves.
//
// Build phase (replaces the old prep kernel): wave w builds one 16-row tile of
// aL (w=0,1: rows of a = b1 + emb_i @ W1[0:32]) or bL (w=2,3: b = emb_j @
// W1[32:64]) via 8x mfma_f32_16x16x32_f16 (K=32=E exactly).
//   A-frag: row=lo, k=8hi+e  -> emb_table[skills[rbase+lo]*32 + 8hi+e]
//   B-frag: k=8hi+e, col=lo  -> W1[(woff+8hi+e)*128 + 16ct+lo]
//   C:      row=4hi+q, col=lo -> LDS tile[(w&1)*16 + 4hi+q][16ct+lo]
//
// Main phase: per 16-pair group, h1 = relu(a_i + b_j) f16 -> MFMA vs W2 ->
// relu,dot(Ws),tanh -> per-block LDS seg accumulation -> private segP slab
// (no global atomics, no zero-init required).
__global__ __launch_bounds__(256) void pair_mlp_fused(
    const int* __restrict__ skills, const float* __restrict__ emb_table,
    const float* __restrict__ W1, const float* __restrict__ b1,
    const float* __restrict__ W2, const float* __restrict__ targets,
    const float* __restrict__ b2, const float* __restrict__ Ws,
    const float* __restrict__ bs,
    float* __restrict__ segP, float* __restrict__ accums_region) {

    int bid = blockIdx.x;
    int tid = threadIdx.x;

    // zero accums[2] + counter + pad (0.f == zero bits for the int counter too)
    if (bid == 0 && tid < 4) accums_region[tid] = 0.f;

    int n = bid / 10;
    int t = bid % 10;
    int ti = 0;
    while ((ti + 1) * (ti + 2) / 2 <= t) ti++;
    int tj = t - ti * (ti + 1) / 2;
    int i0 = ti * 32, j0 = tj * 32;
    bool diag = (ti == tj);

    __shared__ __align__(16) _Float16 aL[32][136];  // +8 pad: 2-way banks (free)
    __shared__ __align__(16) _Float16 bL[32][136];
    __shared__ float tgt[32];
    __shared__ float sT[32], sC[32];

    int lane = tid & 63, wv = tid >> 6;
    int hi = lane >> 4, lo = lane & 15;

    // ---------------- build phase ----------------
    bool isA = (wv < 2);
    int rbase = (isA ? i0 : j0) + (wv & 1) * 16;    // first of this wave's 16 rows
    int woff = isA ? 0 : 32;                        // W1 half (top for a, bottom for b)

    int sk = skills[n * H_ + rbase + lo];
    // A-fragment: emb row for this lane's tile-row (8 consecutive f32 -> f16x8)
    float4 e0 = *(const float4*)(emb_table + (size_t)sk * 32 + 8 * hi);
    float4 e1 = *(const float4*)(emb_table + (size_t)sk * 32 + 8 * hi + 4);
    half8 afrag;
    afrag[0] = (_Float16)e0.x; afrag[1] = (_Float16)e0.y;
    afrag[2] = (_Float16)e0.z; afrag[3] = (_Float16)e0.w;
    afrag[4] = (_Float16)e1.x; afrag[5] = (_Float16)e1.y;
    afrag[6] = (_Float16)e1.z; afrag[7] = (_Float16)e1.w;

    {
        _Float16 (*dst)[136] = isA ? aL : bL;
        int rloc0 = (wv & 1) * 16 + 4 * hi;
        #pragma unroll
        for (int ct = 0; ct < 8; ct++) {
            float cinit = isA ? b1[16 * ct + lo] : 0.f;
            floatx4 accB = (floatx4){cinit, cinit, cinit, cinit};
            half8 bf;
            #pragma unroll
            for (int e = 0; e < 8; e++)
                bf[e] = (_Float16)W1[(woff + 8 * hi + e) * 128 + 16 * ct + lo];
            accB = __builtin_amdgcn_mfma_f32_16x16x32_f16(afrag, bf, accB, 0, 0, 0);
            #pragma unroll
            for (int q = 0; q < 4; q++)
                dst[rloc0 + q][16 * ct + lo] = (_Float16)accB[q];
        }
    }

    if (tid < 32) {
        tgt[tid] = targets[n * H_ + j0 + tid];
        sT[tid] = 0.f;
        sC[tid] = 0.f;
    }

    // W2 B-fragments straight from global f32 (L2-hot, one-time per wave)
    half8 wfrag[4][4];
    #pragma unroll
    for (int kk = 0; kk < 4; kk++)
        #pragma unroll
        for (int nt = 0; nt < 4; nt++) {
            half8 wf;
            #pragma unroll
            for (int e = 0; e < 8; e++)
                wf[e] = (_Float16)W2[(32 * kk + 8 * hi + e) * 64 + 16 * nt + lo];
            wfrag[kk][nt] = wf;
        }

    float b2v[4], wsv[4];
    #pragma unroll
    for (int nt = 0; nt < 4; nt++) {
        b2v[nt] = b2[16 * nt + lo];
        wsv[nt] = Ws[16 * nt + lo];
    }
    float bsv = bs[0];

    __syncthreads();

    // ---------------- main phase ----------------
    for (int g = wv; g < 64; g += 4) {
        int li = g >> 1;        // i - i0 (same for all 16 rows of the group)
        int hf = g & 1;         // which 16-j half
        if (diag && li <= 16 * hf) continue;   // no valid pairs in group

        const _Float16* arow = &aL[li][0];
        const _Float16* brow = &bL[16 * hf + lo][0];   // lane's A-row = its j row

        floatx4 acc[4];
        #pragma unroll
        for (int nt = 0; nt < 4; nt++) acc[nt] = (floatx4){0.f, 0.f, 0.f, 0.f};

        #pragma unroll
        for (int kk = 0; kk < 4; kk++) {
            half8 av = *(const half8*)(arow + 32 * kk + 8 * hi);  // broadcast
            half8 bv = *(const half8*)(brow + 32 * kk + 8 * hi);
            half8 s = av + bv;                       // v_pk_add_f16
            // relu via sign-bit trick
            short8 bits = __builtin_bit_cast(short8, s);
            short8 sgn = bits >> 15;
            bits &= ~sgn;
            half8 h = __builtin_bit_cast(half8, bits);
            acc[0] = __builtin_amdgcn_mfma_f32_16x16x32_f16(h, wfrag[kk][0], acc[0], 0, 0, 0);
            acc[1] = __builtin_amdgcn_mfma_f32_16x16x32_f16(h, wfrag[kk][1], acc[1], 0, 0, 0);
            acc[2] = __builtin_amdgcn_mfma_f32_16x16x32_f16(h, wfrag[kk][2], acc[2], 0, 0, 0);
            acc[3] = __builtin_amdgcn_mfma_f32_16x16x32_f16(h, wfrag[kk][3], acc[3], 0, 0, 0);
        }

        // epilogue: h2 = relu(acc + b2); partial = sum_cols h2*Ws
        // lane holds cols 16*nt+lo for rows 4*hi+r4
        float part[4];
        #pragma unroll
        for (int r4 = 0; r4 < 4; r4++) {
            float p = 0.f;
            #pragma unroll
            for (int nt = 0; nt < 4; nt++)
                p += fmaxf(acc[nt][r4] + b2v[nt], 0.f) * wsv[nt];
            part[r4] = p;
        }
        // reduce across the 16 lanes of a hi-group (cols)
        #pragma unroll
        for (int m = 1; m <= 8; m <<= 1) {
            #pragma unroll
            for (int r4 = 0; r4 < 4; r4++)
                part[r4] += __shfl_xor(part[r4], m, 64);
        }
        // sim + per-i partial for this hi-group's 4 rows
        float sumT = 0.f, sumC = 0.f;
        #pragma unroll
        for (int r4 = 0; r4 < 4; r4++) {
            int srow = 4 * hi + r4;            // row within group
            int lj = 16 * hf + srow;           // j - j0
            bool valid = (!diag) || (li > lj);
            float x = part[r4] + bsv;
            float e2 = __expf(2.f * x);
            float sv = (e2 - 1.f) / (e2 + 1.f);  // tanh
            sv = valid ? sv : 0.f;
            sumT += sv;
            sumC += sv * tgt[lj];
        }
        if (lo == 0) {                          // one lane per hi-group
            atomicAdd(&sT[li], sumT);           // ds_add_f32
            atomicAdd(&sC[li], sumC);
        }
    }

    __syncthreads();
    // private partial slab: no global atomics, no zero-init dependency
    if (tid < 32) {
        segP[(size_t)bid * 64 + tid]      = sT[tid];
        segP[(size_t)bid * 64 + 32 + tid] = sC[tid];
    }
}

// ---------------------------------------------------------------------------
// Kernel 2: per-(n,h) final linear + sigmoid + masked BCE; last block divides.
// grid 64 x 128 (one block per n, 2 waves)
__global__ void finalize(const int* __restrict__ skills,
                         const float* __restrict__ targets,
                         const float* __restrict__ users,
                         const float* __restrict__ items,
                         const float* __restrict__ langs,
                         const void* __restrict__ mask,
                         const float* __restrict__ Wlin,
                         const float* __restrict__ blin,
                         const float* __restrict__ segP,
                         float* __restrict__ out,
                         float* __restrict__ accums,
                         int* __restrict__ counter) {
    int n = blockIdx.x, h = threadIdx.x;
    int nh = n * H_ + h;
    int sk = skills[nh];

    // mask dtype sniff: bool(1B) vs int32(4B). 16 words, in-bounds either way.
    const unsigned* mw = (const unsigned*)mask;
    bool byte_layout = false;
    #pragma unroll
    for (int q = 0; q < 16; q++) byte_layout |= (mw[q] > 1u);
    float m = byte_layout ? (((const unsigned char*)mask)[nh] ? 1.f : 0.f)
                          : (mw[nh] ? 1.f : 0.f);

    // gather this row's seg partials from the <=4 contributing tiles
    int ti = h >> 5, r = h & 31;
    int tb = ti * (ti + 1) / 2;
    float sT = 0.f, sC = 0.f;
    for (int tj = 0; tj <= ti; tj++) {
        const float* p = segP + (size_t)(n * 10 + tb + tj) * 64;
        sT += p[r];
        sC += p[32 + r];
    }

    // per-n constant part: users.Wlin[0:32] + tcf-dot (+blin)
    float tterm = sT * Wlin[OFF_TCF + sk] + sC * Wlin[OFF_TCF2 + sk];
    if (h < 32) tterm += users[n * 32 + h] * Wlin[h];

    __shared__ float cred[2];
    {
        float v = tterm;
        #pragma unroll
        for (int mm = 1; mm <= 32; mm <<= 1) v += __shfl_xor(v, mm, 64);
        if ((h & 63) == 0) cred[h >> 6] = v;
    }
    __syncthreads();
    float c = cred[0] + cred[1] + blin[0];

    float z = c + Wlin[OFF_ONEHOT + sk];
    const float4* ip = (const float4*)(items + (size_t)nh * 32);
    #pragma unroll
    for (int i4 = 0; i4 < 8; i4++) {
        float4 v = ip[i4];
        z += v.x * Wlin[OFF_ITEMS + 4 * i4]     + v.y * Wlin[OFF_ITEMS + 4 * i4 + 1]
           + v.z * Wlin[OFF_ITEMS + 4 * i4 + 2] + v.w * Wlin[OFF_ITEMS + 4 * i4 + 3];
    }
    const float4* lp = (const float4*)(langs + (size_t)nh * 16);
    #pragma unroll
    for (int l4 = 0; l4 < 4; l4++) {
        float4 v = lp[l4];
        z += v.x * Wlin[OFF_LANGS + 4 * l4]     + v.y * Wlin[OFF_LANGS + 4 * l4 + 1]
           + v.z * Wlin[OFF_LANGS + 4 * l4 + 2] + v.w * Wlin[OFF_LANGS + 4 * l4 + 3];
    }

    out[1 + nh] = 1.f / (1.f + __expf(-z));

    float y = targets[nh];
    float bce = fmaxf(z, 0.f) - z * y + log1pf(__expf(-fabsf(z)));

    __shared__ float s1[2], s2[2];
    {
        float x1 = bce * m, x2 = m;
        #pragma unroll
        for (int mm = 1; mm <= 32; mm <<= 1) {
            x1 += __shfl_xor(x1, mm, 64);
            x2 += __shfl_xor(x2, mm, 64);
        }
        if ((h & 63) == 0) { s1[h >> 6] = x1; s2[h >> 6] = x2; }
    }
    __syncthreads();
    if (h == 0) {
        atomicAdd(&accums[0], s1[0] + s1[1]);
        atomicAdd(&accums[1], s2[0] + s2[1]);
        __threadfence();
        if (atomicAdd(counter, 1) == N_ - 1) {       // last block overall
            float a = atomicAdd(&accums[0], 0.f);    // device-coherent read
            float b = atomicAdd(&accums[1], 0.f);
            out[0] = a / fmaxf(b, 1.f);
        }
    }
}

// ---------------------------------------------------------------------------
extern "C" void kernel_launch(void* const* d_in, const int* in_sizes, int n_in,
                              void* d_out, int out_size, void* d_ws, size_t ws_size,
                              hipStream_t stream) {
    const int*   skills  = (const int*)d_in[0];
    const float* targets = (const float*)d_in[1];
    const float* users   = (const float*)d_in[2];
    const float* items   = (const float*)d_in[3];
    const float* langs   = (const float*)d_in[4];
    const void*  mask    = (const void*)d_in[5];
    const float* emb     = (const float*)d_in[6];
    const float* W1      = (const float*)d_in[7];
    const float* b1      = (const float*)d_in[8];
    const float* W2      = (const float*)d_in[9];
    const float* b2      = (const float*)d_in[10];
    const float* Ws      = (const float*)d_in[11];
    const float* bs      = (const float*)d_in[12];
    const float* Wlin    = (const float*)d_in[13];
    const float* blin    = (const float*)d_in[14];

    char* ws = (char*)d_ws;
    float* segP    = (float*)ws;                    // 640*64 f32 = 160 KB
    float* accums  = (float*)(ws + (256u << 10));   // accums[2] + counter + pad
    int*   counter = (int*)(accums + 2);

    pair_mlp_fused<<<N_ * 10, 256, 0, stream>>>(skills, emb, W1, b1, W2, targets,
                                                b2, Ws, bs, segP, accums);
    finalize<<<N_, H_, 0, stream>>>(skills, targets, users, items, langs, mask,
                                    Wlin, blin, segP, (float*)d_out, accums, counter);
}